// Round 7
// baseline (73.100 us; speedup 1.0000x reference)
//
#include <hip/hip_runtime.h>

typedef unsigned int uint;

#define HW (512 * 512)
#define NIMG 64
#define NUQ 6
#define QSTRIDE 528
#define FLB 32768                  // float ring base (3 slots x 12288)
#define SLOTB 12288
#define QRB (32768 + 3 * 12288)    // 69632: quant ring (8 rows x 528)
#define SMEM_BYTES (QRB + 8 * QSTRIDE)   // 73856

// offsets (all dc >= 0; (1,-1) reformulated as (-1,1), transpose-equivalent
// under the final P+P^T symmetrization):
// u0 (0,1)  w1 tag0 lo | u1 (1,1) w2 tag1 lo | u2 (1,0) w1 tag2 lo
// u3 (-1,1) w2 tag0 hi | u4 (0,2) w1 tag1 hi | u5 (2,0) w1 tag2 hi
__device__ __constant__ float UOFF_W[NUQ] = {1.f, 2.f, 1.f, 2.f, 1.f, 1.f};
__device__ __constant__ float NPAIRS[NUQ] = {
    512.f * 511.f, 511.f * 511.f, 511.f * 512.f,
    511.f * 511.f, 512.f * 510.f, 510.f * 512.f};

__device__ __forceinline__ uint q1f(float a, float b, float c) {
    // ((a+b+c)/3 + 1) * 0.5 * 31 == (a+b+c)*(31/6) + 15.5
    float t = fmaf(a + b + c, 5.1666665f, 15.5f);
    t = fminf(fmaxf(t, 0.0f), 31.0f);
    return (uint)t;                       // trunc, matches astype(int32)
}

__global__ __launch_bounds__(256) void glcm_fused(
    const float* __restrict__ in, uint* __restrict__ wire) {
    __shared__ __align__(16) unsigned char smem[SMEM_BYTES];
    const int tid = threadIdx.x;
    const int b = blockIdx.x >> 4;
    const int s = blockIdx.x & 15;
    const int rs = s * 32;
    const int w = tid >> 6;
    const int lane = tid & 63;
    const float* ib = in + (size_t)b * (3 * HW);

    // zero hist (32 KB, includes junk bins)
    {
        uint4 z = make_uint4(0, 0, 0, 0);
        #pragma unroll
        for (int q = 0; q < 8; ++q)
            *(uint4*)(smem + tid * 16 + q * 4096) = z;
    }

    // ---- async stage: chunk cc = 2 rows x 512 px x 3ch floats -> slot cc%3 ----
    auto issue = [&](int cc) {
        const int slot = cc % 3;
        const int R0 = rs - 2 + 2 * cc;
        #pragma unroll
        for (int ch = 0; ch < 3; ++ch) {
            int row = min(max(R0 + (w >> 1), 0), 511);   // clamp: garbage rows never read
            const float* src = ib + ch * HW + row * 512 + (w & 1) * 256 + lane * 4;
            __builtin_amdgcn_global_load_lds(
                (const __attribute__((address_space(1))) void*)src,
                (__attribute__((address_space(3))) void*)(smem + FLB + slot * SLOTB + (ch * 4 + w) * 1024),
                16, 0, 0);
        }
    };

    issue(0);   // prologue: 2 chunks in flight
    issue(1);

    for (int c = 0; c <= 18; ++c) {
        // (A) counted-vmcnt barrier: slot c landed; slot c+1's loads STAY in flight
        if (c < 17) {
            asm volatile("s_waitcnt vmcnt(3) lgkmcnt(0)\n\ts_barrier" ::: "memory");
        } else {
            asm volatile("s_waitcnt vmcnt(0) lgkmcnt(0)\n\ts_barrier" ::: "memory");
        }

        // (B) issue chunk c+2 (lands no earlier than needed; consumed at iter c+2)
        if (c + 2 <= 17) issue(c + 2);

        // (C) histogram chunk h = c-2 (pair rows rs-2+2h, +1) from quant ring
        const int h = c - 2;
        if (h >= 1 && h <= 16) {
            const int lr = tid >> 7;
            const int dq = tid & 127;
            const int R = rs - 2 + 2 * h + lr;
            const unsigned char* qr = smem + QRB;
            const uint* rowL   = (const uint*)(qr + ((R)     & 7) * QSTRIDE);
            const uint* rowLm  = (const uint*)(qr + ((R - 1) & 7) * QSTRIDE);
            const uint* rowLp  = (const uint*)(qr + ((R + 1) & 7) * QSTRIDE);
            const uint* rowLpp = (const uint*)(qr + ((R + 2) & 7) * QSTRIDE);
            uint A = rowL[dq],  A1 = rowL[dq + 1];       // dq=127 -> [128] = pad dword
            uint B = rowLp[dq], B1 = rowLp[dq + 1];
            uint C = rowLm[dq], C1 = rowLm[dq + 1];
            uint D = rowLpp[dq];

            auto pp4 = [&](uint jw, int tagoff, uint inc, int rlo, int rhi) {
                if (R >= rlo && R < rhi) {
                    // addr = (i<<10)|(j<<2): bytes pre-shifted q<<2; pad 0x80 -> junk bin
                    uint a0 = __builtin_amdgcn_perm(A, jw, 0x0C0C0400u) & 0xFCFCu;
                    uint a1 = __builtin_amdgcn_perm(A, jw, 0x0C0C0501u) & 0xFCFCu;
                    uint a2 = __builtin_amdgcn_perm(A, jw, 0x0C0C0602u) & 0xFCFCu;
                    uint a3 = __builtin_amdgcn_perm(A, jw, 0x0C0C0703u) & 0xFCFCu;
                    atomicAdd((uint*)(smem + tagoff + a0), inc);
                    atomicAdd((uint*)(smem + tagoff + a1), inc);
                    atomicAdd((uint*)(smem + tagoff + a2), inc);
                    atomicAdd((uint*)(smem + tagoff + a3), inc);
                }
            };
            pp4(__builtin_amdgcn_alignbyte(A1, A, 1), 0,   1u,     0, 512);  // u0 (0,1)
            pp4(__builtin_amdgcn_alignbyte(B1, B, 1), 256, 1u,     0, 511);  // u1 (1,1)
            pp4(B,                                    512, 1u,     0, 511);  // u2 (1,0)
            pp4(__builtin_amdgcn_alignbyte(C1, C, 1), 0,   65536u, 1, 512);  // u3 (-1,1)
            pp4(__builtin_amdgcn_alignbyte(A1, A, 2), 256, 65536u, 0, 512);  // u4 (0,2)
            pp4(D,                                    512, 65536u, 0, 510);  // u5 (2,0)
        }

        // (D) quantize chunk c: floats (slot c%3) -> quant ring rows (pre-shifted <<2)
        if (c <= 17) {
            const int r = tid >> 7;
            const int c4 = (tid & 127) << 2;
            const int R = rs - 2 + 2 * c + r;
            const float* fb = (const float*)(smem + FLB + (c % 3) * SLOTB);
            float4 f0 = *(const float4*)(fb + 0 * 1024 + r * 512 + c4);
            float4 f1 = *(const float4*)(fb + 1 * 1024 + r * 512 + c4);
            float4 f2 = *(const float4*)(fb + 2 * 1024 + r * 512 + c4);
            uint q = (q1f(f0.x, f1.x, f2.x) << 2)
                   | (q1f(f0.y, f1.y, f2.y) << 10)
                   | (q1f(f0.z, f1.z, f2.z) << 18)
                   | (q1f(f0.w, f1.w, f2.w) << 26);
            unsigned char* qrw = smem + QRB + ((R) & 7) * QSTRIDE;
            *(uint*)(qrw + c4) = q;
            if ((tid & 127) == 127)   // sentinel pads, cols 512..527
                *(uint4*)(qrw + 512) =
                    make_uint4(0x80808080u, 0x80808080u, 0x80808080u, 0x80808080u);
        }
    }

    __syncthreads();   // final: all ds_adds visible

    // ---- flush: compress 32 KB (valid bins only) -> 12 KB wire, plain stores ----
    uint* hb = wire + (size_t)blockIdx.x * 3072;
    const uint* hist = (const uint*)smem;
    #pragma unroll
    for (int qq = 0; qq < 12; ++qq) {
        int o = tid + qq * 256;          // o = tag*1024 + i*32 + j
        int tg = o >> 10, ij = o & 1023;
        int i = ij >> 5, j = ij & 31;
        hb[o] = hist[(i << 8) | (tg << 6) | j];
    }
}

// ---- features + weighted offset average, one block per image ----
__global__ __launch_bounds__(256) void feature_out_kernel(
    const uint* __restrict__ wire, float* __restrict__ out) {
    const int b = blockIdx.x;
    __shared__ uint cnt[NUQ][1024];      // 24 KB
    __shared__ float fred[NUQ][4];
    const int tid = threadIdx.x, wid = tid >> 6, lane = tid & 63;

    for (int u = wid; u < NUQ; u += 4) {
        const int tg = (u < 3) ? u : u - 3;
        const int sh = (u < 3) ? 0 : 16;
        const uint* p = wire + (size_t)b * (16 * 3072) + tg * 1024;
        for (int ij = lane; ij < 1024; ij += 64) {
            uint acc = 0;
            #pragma unroll
            for (int st = 0; st < 16; ++st)
                acc += (p[(size_t)st * 3072 + ij] >> sh) & 0xFFFFu;
            cnt[u][ij] = acc;
        }
    }
    __syncthreads();

    for (int u = wid; u < NUQ; u += 4) {
        const float inv_total = 1.0f / (2.0f * NPAIRS[u]);
        float c_sum = 0, h_sum = 0, e_sum = 0, m1 = 0, m2 = 0, m12 = 0;
        for (int k = lane; k < 1024; k += 64) {
            int i = k >> 5, j = k & 31;
            float sym = (float)(cnt[u][k] + cnt[u][(j << 5) | i]);
            float P = sym * inv_total;
            float d = (float)(i - j);
            float d2 = d * d;
            float fi = (float)i, fj = (float)j;
            c_sum += P * d2;
            h_sum += P / (1.0f + d2);
            e_sum += P * P;
            m1 += P * fi; m2 += P * fi * fi; m12 += P * fi * fj;
        }
        #pragma unroll
        for (int sft = 32; sft > 0; sft >>= 1) {
            c_sum += __shfl_down(c_sum, sft);
            h_sum += __shfl_down(h_sum, sft);
            e_sum += __shfl_down(e_sum, sft);
            m1 += __shfl_down(m1, sft);
            m2 += __shfl_down(m2, sft);
            m12 += __shfl_down(m12, sft);
        }
        if (lane == 0) {
            float mu = m1, var = m2 - mu * mu, cov = m12 - mu * mu;
            float corr = (var > 1e-15f) ? cov / var : 1.0f;  // std_i*std_j = var (P symmetric)
            fred[u][0] = c_sum; fred[u][1] = h_sum;
            fred[u][2] = sqrtf(e_sum); fred[u][3] = corr;
        }
    }
    __syncthreads();
    if (tid < 4) {
        float acc = 0.f;
        #pragma unroll
        for (int u = 0; u < NUQ; ++u) acc += UOFF_W[u] * fred[u][tid];
        out[tid * NIMG + b] = acc * 0.125f;
    }
}

extern "C" void kernel_launch(void* const* d_in, const int* in_sizes, int n_in,
                              void* d_out, int out_size, void* d_ws, size_t ws_size,
                              hipStream_t stream) {
    const float* images = (const float*)d_in[0];
    float* out = (float*)d_out;
    uint* wire = (uint*)d_ws;            // 1024 blocks x 3072 u32 = 12.6 MB

    glcm_fused<<<NIMG * 16, 256, 0, stream>>>(images, wire);
    feature_out_kernel<<<NIMG, 256, 0, stream>>>(wire, out);
}